// Round 1
// baseline (1758.317 us; speedup 1.0000x reference)
//
#include <hip/hip_runtime.h>
#include <hip/hip_bf16.h>

#define D_MODEL 1024
#define N_HEADS 16
#define HEAD_DIM 64
#define SEQ 2048
#define BATCH 2

// ---------------------------------------------------------------------------
// GEMM: C[M,N] = A[M,K] @ B[K,N] + bias[N]
// 64x64 output tile per block, BK=16, 256 threads, 4x4 register micro-tile.
// ---------------------------------------------------------------------------
__global__ __launch_bounds__(256) void gemm_bias_kernel(
    const float* __restrict__ A, const float* __restrict__ B,
    const float* __restrict__ bias, float* __restrict__ C,
    int M, int N, int K) {
  __shared__ float As[16][64];  // As[k][m]
  __shared__ float Bs[16][64];  // Bs[k][n]
  const int tid = threadIdx.x;
  const int bm = blockIdx.y * 64;
  const int bn = blockIdx.x * 64;
  const int ty = tid >> 4;   // 0..15 -> rows bm + ty*4 .. +3
  const int tx = tid & 15;   // 0..15 -> cols bn + tx*4 .. +3

  const int arow = tid >> 2;         // 0..63
  const int ac4  = (tid & 3) << 2;   // 0,4,8,12
  const int brow = tid >> 4;         // 0..15
  const int bc4  = (tid & 15) << 2;  // 0..60
  const float* aptr = A + (size_t)(bm + arow) * K + ac4;
  const float* bptr = B + (size_t)brow * N + bn + bc4;

  float acc[4][4] = {};

  for (int k0 = 0; k0 < K; k0 += 16) {
    const float4 av = *(const float4*)(aptr + k0);
    const float4 bv = *(const float4*)(bptr + (size_t)k0 * N);
    As[ac4 + 0][arow] = av.x;
    As[ac4 + 1][arow] = av.y;
    As[ac4 + 2][arow] = av.z;
    As[ac4 + 3][arow] = av.w;
    *(float4*)&Bs[brow][bc4] = bv;
    __syncthreads();
#pragma unroll
    for (int k = 0; k < 16; ++k) {
      const float4 a = *(const float4*)&As[k][ty << 2];
      const float4 b = *(const float4*)&Bs[k][tx << 2];
      acc[0][0] += a.x * b.x; acc[0][1] += a.x * b.y; acc[0][2] += a.x * b.z; acc[0][3] += a.x * b.w;
      acc[1][0] += a.y * b.x; acc[1][1] += a.y * b.y; acc[1][2] += a.y * b.z; acc[1][3] += a.y * b.w;
      acc[2][0] += a.z * b.x; acc[2][1] += a.z * b.y; acc[2][2] += a.z * b.z; acc[2][3] += a.z * b.w;
      acc[3][0] += a.w * b.x; acc[3][1] += a.w * b.y; acc[3][2] += a.w * b.z; acc[3][3] += a.w * b.w;
    }
    __syncthreads();
  }

  const float* bsrc = bias + bn + (tx << 2);
  const float b0 = bsrc[0], b1 = bsrc[1], b2 = bsrc[2], b3 = bsrc[3];
#pragma unroll
  for (int i = 0; i < 4; ++i) {
    const int row = bm + (ty << 2) + i;
    float4 r;
    r.x = acc[i][0] + b0;
    r.y = acc[i][1] + b1;
    r.z = acc[i][2] + b2;
    r.w = acc[i][3] + b3;
    *(float4*)(C + (size_t)row * N + bn + (tx << 2)) = r;
  }
}

// ---------------------------------------------------------------------------
// Flash-style attention, fp32.
// Block = (query tile of 64, head h, batch b), 256 threads.
// Thread t owns query row q = t/4 and 16 of 64 score columns / 16 of 64 output
// dims (sub = t&3). Online softmax over 64-key tiles streamed through LDS.
// qkv layout: [B*S][3*D] with Q at col h*64, K at 1024+h*64, V at 2048+h*64.
// attn_out layout: [B*S][D] with head h at col h*64.
// ---------------------------------------------------------------------------
__global__ __launch_bounds__(256) void attn_kernel(
    const float* __restrict__ qkv, float* __restrict__ attn_out) {
  __shared__ float QPs[64][68];  // Q staging, then P tile (overlaid)
  __shared__ float Ks[64][68];
  __shared__ float Vs[64][68];
  const int qt = blockIdx.x;
  const int h  = blockIdx.y;
  const int b  = blockIdx.z;
  const int tid = threadIdx.x;
  const size_t rs = 3 * D_MODEL;  // 3072 floats per qkv row

  const float* qbase = qkv + ((size_t)b * SEQ + (size_t)qt * 64) * rs + h * HEAD_DIM;
  const float* kbase = qkv + ((size_t)b * SEQ) * rs + D_MODEL + h * HEAD_DIM;
  const float* vbase = kbase + D_MODEL;

  // stage Q tile [64][64]
  for (int i = tid; i < 64 * 16; i += 256) {
    const int r = i >> 4, c = (i & 15) << 2;
    *(float4*)&QPs[r][c] = *(const float4*)(qbase + (size_t)r * rs + c);
  }
  __syncthreads();

  const int q = tid >> 2, sub = tid & 3;
  float4 qv[16];
#pragma unroll
  for (int i = 0; i < 16; ++i) qv[i] = *(const float4*)&QPs[q][i << 2];

  float m_run = -1e30f, l_run = 0.f;
  float4 o[4];
#pragma unroll
  for (int i = 0; i < 4; ++i) o[i] = make_float4(0.f, 0.f, 0.f, 0.f);

  for (int kt = 0; kt < SEQ; kt += 64) {
    __syncthreads();  // protects qv reg-load (iter 0) / prev-iter Ps & Vs reads
    for (int i = tid; i < 64 * 16; i += 256) {
      const int r = i >> 4, c = (i & 15) << 2;
      *(float4*)&Ks[r][c] = *(const float4*)(kbase + (size_t)(kt + r) * rs + c);
      *(float4*)&Vs[r][c] = *(const float4*)(vbase + (size_t)(kt + r) * rs + c);
    }
    __syncthreads();

    // phase 1: scores for row q, keys sub*16 .. sub*16+15
    float s[16];
#pragma unroll
    for (int kk = 0; kk < 16; ++kk) {
      const int krow = (sub << 4) + kk;
      float acc = 0.f;
#pragma unroll
      for (int d4 = 0; d4 < 16; ++d4) {
        const float4 k4 = *(const float4*)&Ks[krow][d4 << 2];
        acc += qv[d4].x * k4.x + qv[d4].y * k4.y + qv[d4].z * k4.z + qv[d4].w * k4.w;
      }
      s[kk] = acc * 0.125f;  // 1/sqrt(64)
    }

    // online softmax (4 lanes per row cooperate; groups are lane-aligned)
    float mx = s[0];
#pragma unroll
    for (int kk = 1; kk < 16; ++kk) mx = fmaxf(mx, s[kk]);
    mx = fmaxf(mx, __shfl_xor(mx, 1, 4));
    mx = fmaxf(mx, __shfl_xor(mx, 2, 4));
    const float m_new = fmaxf(m_run, mx);
    const float rescale = __expf(m_run - m_new);
    float lsum = 0.f;
#pragma unroll
    for (int kk = 0; kk < 16; ++kk) {
      s[kk] = __expf(s[kk] - m_new);
      lsum += s[kk];
    }
    lsum += __shfl_xor(lsum, 1, 4);
    lsum += __shfl_xor(lsum, 2, 4);
    l_run = l_run * rescale + lsum;
    m_run = m_new;
#pragma unroll
    for (int i = 0; i < 4; ++i) {
      o[i].x *= rescale; o[i].y *= rescale; o[i].z *= rescale; o[i].w *= rescale;
    }

    // publish P tile (overlays Q staging buffer; safe: qv already in regs)
#pragma unroll
    for (int kk = 0; kk < 16; ++kk) QPs[q][(sub << 4) + kk] = s[kk];
    __syncthreads();

    // phase 2: O[q][sub*16 .. +15] += P[q][:] @ V[:][dims]
#pragma unroll
    for (int k4 = 0; k4 < 16; ++k4) {
      const float4 p4 = *(const float4*)&QPs[q][k4 << 2];
#pragma unroll
      for (int j = 0; j < 4; ++j) {
        const float p = (j == 0) ? p4.x : (j == 1) ? p4.y : (j == 2) ? p4.z : p4.w;
        const int krow = (k4 << 2) + j;
#pragma unroll
        for (int i = 0; i < 4; ++i) {
          const float4 v4 = *(const float4*)&Vs[krow][(sub << 4) + (i << 2)];
          o[i].x += p * v4.x; o[i].y += p * v4.y; o[i].z += p * v4.z; o[i].w += p * v4.w;
        }
      }
    }
  }

  const float inv = 1.f / l_run;
  float* dst = attn_out + ((size_t)b * SEQ + (size_t)qt * 64 + q) * D_MODEL + h * HEAD_DIM + (sub << 4);
#pragma unroll
  for (int i = 0; i < 4; ++i) {
    float4 r = o[i];
    r.x *= inv; r.y *= inv; r.z *= inv; r.w *= inv;
    ((float4*)dst)[i] = r;
  }
}

// ---------------------------------------------------------------------------
extern "C" void kernel_launch(void* const* d_in, const int* in_sizes, int n_in,
                              void* d_out, int out_size, void* d_ws, size_t ws_size,
                              hipStream_t stream) {
  const float* x     = (const float*)d_in[0];  // [2,2048,1024]
  const float* w_qkv = (const float*)d_in[1];  // [1024,3072]
  const float* b_qkv = (const float*)d_in[2];  // [3072]
  const float* w_o   = (const float*)d_in[3];  // [1024,1024]
  const float* b_o   = (const float*)d_in[4];  // [1024]
  float* out = (float*)d_out;                  // [2,2048,1024]

  float* qkv  = (float*)d_ws;                        // [4096][3072] = 50.3 MB
  float* attn = qkv + (size_t)4096 * 3072;           // [4096][1024] = 16.8 MB

  const dim3 blk(256);
  // GEMM1: x @ w_qkv + b_qkv -> qkv
  gemm_bias_kernel<<<dim3(3072 / 64, 4096 / 64), blk, 0, stream>>>(
      x, w_qkv, b_qkv, qkv, 4096, 3072, 1024);
  // attention
  attn_kernel<<<dim3(SEQ / 64, N_HEADS, BATCH), blk, 0, stream>>>(qkv, attn);
  // GEMM2: attn @ w_o + b_o -> out
  gemm_bias_kernel<<<dim3(1024 / 64, 4096 / 64), blk, 0, stream>>>(
      attn, w_o, b_o, out, 4096, 1024, 1024);
}

// Round 3
// 167.698 us; speedup vs baseline: 10.4850x; 10.4850x over previous
//
#include <hip/hip_runtime.h>
#include <hip/hip_bf16.h>

typedef unsigned int u32;
typedef unsigned short u16;
typedef __attribute__((ext_vector_type(8))) short bf16x8;   // MFMA A/B frag (8 bf16)
typedef __attribute__((ext_vector_type(4))) float f32x4;    // MFMA C/D frag
typedef __attribute__((ext_vector_type(8))) u16 u16x8;

#define MFMA_16x16x32(A, B, C) __builtin_amdgcn_mfma_f32_16x16x32_bf16(A, B, C, 0, 0, 0)

__device__ __forceinline__ u16 f2bf(float f) {
  union { float f; u32 u; } v;
  v.f = f;
  return (u16)((v.u + 0x7fffu + ((v.u >> 16) & 1u)) >> 16);  // RNE
}

__device__ __forceinline__ void g2l16(const void* g, void* l) {
  __builtin_amdgcn_global_load_lds(
      (const __attribute__((address_space(1))) u32*)g,
      (__attribute__((address_space(3))) u32*)l, 16, 0, 0);
}

// ---------------------------------------------------------------------------
// x (fp32) -> bf16, 8 elems/thread
// ---------------------------------------------------------------------------
__global__ __launch_bounds__(256) void xcvt(const float* __restrict__ in,
                                            u16* __restrict__ out, int n8) {
  const int i = blockIdx.x * 256 + threadIdx.x;
  if (i >= n8) return;
  const float4* p = (const float4*)in + (size_t)i * 2;
  const float4 a = p[0], b = p[1];
  u16x8 o;
  o[0] = f2bf(a.x); o[1] = f2bf(a.y); o[2] = f2bf(a.z); o[3] = f2bf(a.w);
  o[4] = f2bf(b.x); o[5] = f2bf(b.y); o[6] = f2bf(b.z); o[7] = f2bf(b.w);
  *((u16x8*)out + i) = o;
}

// ---------------------------------------------------------------------------
// out[c][r] = bf16(in[r][c])  (weights -> B^T layout), 32x32 tiles
// ---------------------------------------------------------------------------
__global__ __launch_bounds__(256) void wtrans(const float* __restrict__ in,
                                              u16* __restrict__ out, int R, int C) {
  __shared__ float t[32][33];
  const int r0 = blockIdx.y << 5, c0 = blockIdx.x << 5;
  const int tr = threadIdx.x >> 3, tc = (threadIdx.x & 7) << 2;
  const float4 v = *(const float4*)(in + (size_t)(r0 + tr) * C + c0 + tc);
  t[tr][tc] = v.x; t[tr][tc + 1] = v.y; t[tr][tc + 2] = v.z; t[tr][tc + 3] = v.w;
  __syncthreads();
  u32 p0 = (u32)f2bf(t[tc][tr]) | ((u32)f2bf(t[tc + 1][tr]) << 16);
  u32 p1 = (u32)f2bf(t[tc + 2][tr]) | ((u32)f2bf(t[tc + 3][tr]) << 16);
  u32* dst = (u32*)(out + (size_t)(c0 + tr) * R + r0 + tc);
  dst[0] = p0;
  dst[1] = p1;
}

// ---------------------------------------------------------------------------
// bf16 MFMA GEMM: C[M,N] = A[M,K] @ Bt[N,K]^T + bias.  128x128 tile, BK=32,
// 4 waves (2x2 of 64x64), global_load_lds staging, XOR-swizzled LDS
// (64B rows: block ^= (row>>1)&3  -> 2-way conflicts only).
// ---------------------------------------------------------------------------
template <int OUT_BF16>
__global__ __launch_bounds__(256) void gemm_mfma(
    const u16* __restrict__ A, const u16* __restrict__ Bt,
    const float* __restrict__ bias, void* __restrict__ Cv, int N, int K) {
  __shared__ u16 As[128 * 32];
  __shared__ u16 Bs[128 * 32];
  const int tid = threadIdx.x;
  const int l = tid & 63, g = l >> 4, lr = l & 15;
  const int w = tid >> 6;
  const int wm = (w >> 1) << 6, wn = (w & 1) << 6;
  const int bm = blockIdx.y << 7, bn = blockIdx.x << 7;

  f32x4 acc[4][4];
  const f32x4 zero = {0.f, 0.f, 0.f, 0.f};
#pragma unroll
  for (int i = 0; i < 4; ++i)
#pragma unroll
    for (int j = 0; j < 4; ++j) acc[i][j] = zero;

  // staging: 512 16B chunks per tile per matrix; chunk bi -> row=bi>>2, phys
  // block bi&3, logical block = phys ^ ((row>>1)&3)
  const int bi0 = tid, bi1 = 256 + tid;
  const int r0 = bi0 >> 2, lb0 = (bi0 & 3) ^ ((r0 >> 1) & 3);
  const int r1 = bi1 >> 2, lb1 = (bi1 & 3) ^ ((r1 >> 1) & 3);
  const u16* a0 = A + (size_t)(bm + r0) * K + lb0 * 8;
  const u16* a1 = A + (size_t)(bm + r1) * K + lb1 * 8;
  const u16* b0 = Bt + (size_t)(bn + r0) * K + lb0 * 8;
  const u16* b1 = Bt + (size_t)(bn + r1) * K + lb1 * 8;

  const int swA = (lr >> 1) & 3;
  const int aoff = (wm + lr) * 64 + ((g ^ swA) << 4);
  const int boff = (wn + lr) * 64 + ((g ^ swA) << 4);

  for (int k0 = 0; k0 < K; k0 += 32) {
    __syncthreads();
    g2l16(a0 + k0, (char*)As + bi0 * 16);
    g2l16(a1 + k0, (char*)As + bi1 * 16);
    g2l16(b0 + k0, (char*)Bs + bi0 * 16);
    g2l16(b1 + k0, (char*)Bs + bi1 * 16);
    __syncthreads();
    bf16x8 af[4], bfv[4];
#pragma unroll
    for (int mi = 0; mi < 4; ++mi)
      af[mi] = *(const bf16x8*)((const char*)As + aoff + mi * 1024);
#pragma unroll
    for (int ni = 0; ni < 4; ++ni)
      bfv[ni] = *(const bf16x8*)((const char*)Bs + boff + ni * 1024);
#pragma unroll
    for (int mi = 0; mi < 4; ++mi)
#pragma unroll
      for (int ni = 0; ni < 4; ++ni)
        acc[mi][ni] = MFMA_16x16x32(af[mi], bfv[ni], acc[mi][ni]);
  }

  float bv[4];
#pragma unroll
  for (int ni = 0; ni < 4; ++ni) bv[ni] = bias[bn + wn + ni * 16 + lr];
  const int crow = bm + wm + (g << 2);
  const int ccol = bn + wn + lr;
  if (OUT_BF16) {
    u16* C = (u16*)Cv;
#pragma unroll
    for (int mi = 0; mi < 4; ++mi)
#pragma unroll
      for (int ni = 0; ni < 4; ++ni)
#pragma unroll
        for (int j = 0; j < 4; ++j)
          C[(size_t)(crow + mi * 16 + j) * N + ccol + ni * 16] =
              f2bf(acc[mi][ni][j] + bv[ni]);
  } else {
    float* C = (float*)Cv;
#pragma unroll
    for (int mi = 0; mi < 4; ++mi)
#pragma unroll
      for (int ni = 0; ni < 4; ++ni)
#pragma unroll
        for (int j = 0; j < 4; ++j)
          C[(size_t)(crow + mi * 16 + j) * N + ccol + ni * 16] =
              acc[mi][ni][j] + bv[ni];
  }
}

// ---------------------------------------------------------------------------
// V-transpose: qkv_b[.., 2048+h*64+d] -> vt[(b*16+h)*64+d][s]  (bf16)
// wave = (b,h,s-tile of 64, d-chunk of 8); coalesced 2B writes along s.
// ---------------------------------------------------------------------------
__global__ __launch_bounds__(256) void vtrans(const u16* __restrict__ qkvb,
                                              u16* __restrict__ vt) {
  const int wid = (blockIdx.x << 2) + (threadIdx.x >> 6);
  const int l = threadIdx.x & 63;
  const int dc = wid & 7, st = (wid >> 3) & 31, h = (wid >> 8) & 15, b = wid >> 12;
  const int s = (st << 6) + l;
  const u16x8 v = *(const u16x8*)(qkvb + (size_t)(b * 2048 + s) * 3072 + 2048 + h * 64 + dc * 8);
  u16* dst = vt + ((size_t)(((b << 4) + h) << 6) + (dc << 3)) * 2048 + s;
#pragma unroll
  for (int j = 0; j < 8; ++j) dst[(size_t)j * 2048] = v[j];
}

// ---------------------------------------------------------------------------
// Flash attention, bf16 MFMA. Block = (qtile 64, h, b), 4 waves x 16 q-rows.
// Swapped QK^T (St[64k][16q] = K·Q^T) so softmax reduce = 2 shuffles; P
// bounced through per-wave swizzled LDS into the PV A-operand. K/V/Q tiles
// staged with global_load_lds + pre-swizzled source (block ^= row&7).
// ---------------------------------------------------------------------------
__global__ __launch_bounds__(256) void attn_mfma(
    const u16* __restrict__ qkvb, const u16* __restrict__ vt,
    u16* __restrict__ attnb) {
  __shared__ u16 Qs[64 * 64];
  __shared__ u16 Ks[64 * 64];
  __shared__ u16 Vs[64 * 64];
  __shared__ u16 Ps[4][16 * 64];

  const int qt = blockIdx.x, h = blockIdx.y, b = blockIdx.z;
  const int tid = threadIdx.x, w = tid >> 6, l = tid & 63;
  const int g = l >> 4, lr = l & 15, sw = lr & 7;
  const size_t sb = (size_t)b * 2048;
  const f32x4 zero = {0.f, 0.f, 0.f, 0.f};

  const int bi0 = tid, bi1 = 256 + tid;
  const int sr0 = bi0 >> 3, slb0 = (bi0 & 7) ^ (sr0 & 7);
  const int sr1 = bi1 >> 3, slb1 = (bi1 & 7) ^ (sr1 & 7);

  {  // stage Q (rows = q, 64 cols hd)
    const u16* qb = qkvb + (sb + (size_t)qt * 64) * 3072 + h * 64;
    g2l16(qb + (size_t)sr0 * 3072 + slb0 * 8, (char*)Qs + bi0 * 16);
    g2l16(qb + (size_t)sr1 * 3072 + slb1 * 8, (char*)Qs + bi1 * 16);
  }
  __syncthreads();
  bf16x8 qf0, qf1;  // B-operand frags: lane q-col = lr (wave row w*16+lr)
  {
    const int row = (w << 4) + lr;
    qf0 = *(const bf16x8*)((const char*)Qs + row * 128 + ((g ^ sw) << 4));
    qf1 = *(const bf16x8*)((const char*)Qs + row * 128 + (((4 + g) ^ sw) << 4));
  }

  float m_run = -1e30f, l_run = 0.f;
  f32x4 o[4];
#pragma unroll
  for (int i = 0; i < 4; ++i) o[i] = zero;

  const u16* kb = qkvb + sb * 3072 + 1024 + h * 64;
  const u16* vb = vt + ((size_t)((b << 4) + h) << 6) * 2048;
  u16* pw = &Ps[w][0];

  for (int kt = 0; kt < 32; ++kt) {
    __syncthreads();
    const size_t ko = (size_t)kt << 6;
    g2l16(kb + (ko + sr0) * 3072 + slb0 * 8, (char*)Ks + bi0 * 16);
    g2l16(kb + (ko + sr1) * 3072 + slb1 * 8, (char*)Ks + bi1 * 16);
    g2l16(vb + (size_t)sr0 * 2048 + ko + slb0 * 8, (char*)Vs + bi0 * 16);
    g2l16(vb + (size_t)sr1 * 2048 + ko + slb1 * 8, (char*)Vs + bi1 * 16);
    __syncthreads();

    // QK^T (swapped): St[f][j] = S^T[key = f*16 + g*4 + j][q = lr]
    f32x4 st[4];
#pragma unroll
    for (int f = 0; f < 4; ++f) {
      st[f] = zero;
      const char* krow = (const char*)Ks + (f * 16 + lr) * 128;
      const bf16x8 k0 = *(const bf16x8*)(krow + ((g ^ sw) << 4));
      const bf16x8 k1 = *(const bf16x8*)(krow + (((4 + g) ^ sw) << 4));
      st[f] = MFMA_16x16x32(k0, qf0, st[f]);
      st[f] = MFMA_16x16x32(k1, qf1, st[f]);
    }

    // online softmax over 64 keys for q = lr (2 shuffles for the reduce)
    float mx = -1e30f;
#pragma unroll
    for (int f = 0; f < 4; ++f)
#pragma unroll
      for (int j = 0; j < 4; ++j) {
        st[f][j] *= 0.125f;
        mx = fmaxf(mx, st[f][j]);
      }
    mx = fmaxf(mx, __shfl_xor(mx, 16));
    mx = fmaxf(mx, __shfl_xor(mx, 32));
    const float m_new = fmaxf(m_run, mx);
    const float resc = __expf(m_run - m_new);
    float lsum = 0.f;
#pragma unroll
    for (int f = 0; f < 4; ++f)
#pragma unroll
      for (int j = 0; j < 4; ++j) {
        const float e = __expf(st[f][j] - m_new);
        st[f][j] = e;
        lsum += e;
      }
    lsum += __shfl_xor(lsum, 16);
    lsum += __shfl_xor(lsum, 32);
    l_run = l_run * resc + lsum;
    m_run = m_new;

    // publish P[16q][64k] (bf16, block-swizzled by q&7), per-wave buffer
#pragma unroll
    for (int f = 0; f < 4; ++f) {
      const u32 lo = (u32)f2bf(st[f][0]) | ((u32)f2bf(st[f][1]) << 16);
      const u32 hi = (u32)f2bf(st[f][2]) | ((u32)f2bf(st[f][3]) << 16);
      const int pb = ((f << 1) + (g >> 1)) ^ sw;
      u32* dst = (u32*)((char*)pw + lr * 128 + (pb << 4) + ((g & 1) << 3));
      dst[0] = lo;
      dst[1] = hi;
    }
    asm volatile("" ::: "memory");  // order P write (u32) before P read (bf16x8)

    // rescale O (O rows q = g*4+j live in different lanes than softmax space)
    float rs[4];
#pragma unroll
    for (int j = 0; j < 4; ++j) rs[j] = __shfl(resc, (g << 2) + j);
#pragma unroll
    for (int nf = 0; nf < 4; ++nf)
#pragma unroll
      for (int j = 0; j < 4; ++j) o[nf][j] *= rs[j];

    // PV: O[16q][64d] += P[16q][64k] @ V[64k][64d]
    const bf16x8 pa0 = *(const bf16x8*)((const char*)pw + lr * 128 + ((g ^ sw) << 4));
    const bf16x8 pa1 = *(const bf16x8*)((const char*)pw + lr * 128 + (((4 + g) ^ sw) << 4));
#pragma unroll
    for (int nf = 0; nf < 4; ++nf) {
      const char* vrow = (const char*)Vs + (nf * 16 + lr) * 128;
      const bf16x8 v0 = *(const bf16x8*)(vrow + ((g ^ sw) << 4));
      const bf16x8 v1 = *(const bf16x8*)(vrow + (((4 + g) ^ sw) << 4));
      o[nf] = MFMA_16x16x32(pa0, v0, o[nf]);
      o[nf] = MFMA_16x16x32(pa1, v1, o[nf]);
    }
  }

  const float invl = 1.f / l_run;
  float iv[4];
#pragma unroll
  for (int j = 0; j < 4; ++j) iv[j] = __shfl(invl, (g << 2) + j);
  u16* obase = attnb + (sb + (size_t)qt * 64 + (w << 4)) * 1024 + h * 64;
#pragma unroll
  for (int nf = 0; nf < 4; ++nf)
#pragma unroll
    for (int j = 0; j < 4; ++j)
      obase[(size_t)((g << 2) + j) * 1024 + nf * 16 + lr] = f2bf(o[nf][j] * iv[j]);
}

// ---------------------------------------------------------------------------
extern "C" void kernel_launch(void* const* d_in, const int* in_sizes, int n_in,
                              void* d_out, int out_size, void* d_ws, size_t ws_size,
                              hipStream_t stream) {
  const float* x     = (const float*)d_in[0];  // [2,2048,1024]
  const float* w_qkv = (const float*)d_in[1];  // [1024,3072]
  const float* b_qkv = (const float*)d_in[2];  // [3072]
  const float* w_o   = (const float*)d_in[3];  // [1024,1024]
  const float* b_o   = (const float*)d_in[4];  // [1024]
  float* out = (float*)d_out;

  // workspace (bf16), 56 MB total
  u16* xb    = (u16*)d_ws;                       // 4096*1024
  u16* wqkvt = xb + (size_t)4096 * 1024;         // 3072*1024 (B^T)
  u16* wot   = wqkvt + (size_t)3072 * 1024;      // 1024*1024 (B^T)
  u16* qkvb  = wot + (size_t)1024 * 1024;        // 4096*3072
  u16* vtb   = qkvb + (size_t)4096 * 3072;       // 2*16*64*2048
  u16* attnb = vtb + (size_t)2 * 16 * 64 * 2048; // 4096*1024

  xcvt<<<dim3(2048), dim3(256), 0, stream>>>(x, xb, 4096 * 1024 / 8);
  wtrans<<<dim3(96, 32), dim3(256), 0, stream>>>(w_qkv, wqkvt, 1024, 3072);
  wtrans<<<dim3(32, 32), dim3(256), 0, stream>>>(w_o, wot, 1024, 1024);

  gemm_mfma<1><<<dim3(24, 32), dim3(256), 0, stream>>>(xb, wqkvt, b_qkv, qkvb, 3072, 1024);

  vtrans<<<dim3(2048), dim3(256), 0, stream>>>(qkvb, vtb);
  attn_mfma<<<dim3(32, 16, 2), dim3(256), 0, stream>>>(qkvb, vtb, attnb);

  gemm_mfma<0><<<dim3(8, 32), dim3(256), 0, stream>>>(attnb, wot, b_o, out, 1024, 1024);
}

// Round 4
// 156.238 us; speedup vs baseline: 11.2541x; 1.0733x over previous
//
#include <hip/hip_runtime.h>
#include <hip/hip_bf16.h>

typedef unsigned int u32;
typedef unsigned short u16;
typedef __attribute__((ext_vector_type(8))) short bf16x8;   // MFMA A/B frag (8 bf16)
typedef __attribute__((ext_vector_type(4))) float f32x4;    // MFMA C/D frag
typedef __attribute__((ext_vector_type(8))) u16 u16x8;
typedef __attribute__((ext_vector_type(2))) u32 u32x2;

#define MFMA_16x16x32(A, B, C) __builtin_amdgcn_mfma_f32_16x16x32_bf16(A, B, C, 0, 0, 0)

// 0.125 (1/sqrt(64)) * log2(e): folded into Q weights/bias -> scores in exp2 domain
#define C_SCALE 0.1803368801111244f

__device__ __forceinline__ u16 f2bf(float f) {   // RNE via native cast (v_cvt_pk-able)
  __hip_bfloat16 h = __float2bfloat16(f);
  u16 u;
  __builtin_memcpy(&u, &h, 2);
  return u;
}

__device__ __forceinline__ float exp2fast(float x) {
#if __has_builtin(__builtin_amdgcn_exp2f)
  return __builtin_amdgcn_exp2f(x);
#else
  return exp2f(x);
#endif
}

__device__ __forceinline__ void g2l16(const void* g, void* l) {
  __builtin_amdgcn_global_load_lds(
      (const __attribute__((address_space(1))) u32*)g,
      (__attribute__((address_space(3))) u32*)l, 16, 0, 0);
}

// ---------------------------------------------------------------------------
// x (fp32) -> bf16, 8 elems/thread
// ---------------------------------------------------------------------------
__global__ __launch_bounds__(256) void xcvt(const float* __restrict__ in,
                                            u16* __restrict__ out, int n8) {
  const int i = blockIdx.x * 256 + threadIdx.x;
  if (i >= n8) return;
  const float4* p = (const float4*)in + (size_t)i * 2;
  const float4 a = p[0], b = p[1];
  u16x8 o;
  o[0] = f2bf(a.x); o[1] = f2bf(a.y); o[2] = f2bf(a.z); o[3] = f2bf(a.w);
  o[4] = f2bf(b.x); o[5] = f2bf(b.y); o[6] = f2bf(b.z); o[7] = f2bf(b.w);
  *((u16x8*)out + i) = o;
}

// ---------------------------------------------------------------------------
// out[c][r] = bf16(in[r][c] * (c<scale_n ? scale : 1))  (weights -> B^T layout)
// ---------------------------------------------------------------------------
__global__ __launch_bounds__(256) void wtrans(const float* __restrict__ in,
                                              u16* __restrict__ out, int R, int C,
                                              int scale_n, float scale) {
  __shared__ float t[32][33];
  const int r0 = blockIdx.y << 5, c0 = blockIdx.x << 5;
  const int tr = threadIdx.x >> 3, tc = (threadIdx.x & 7) << 2;
  const float4 v = *(const float4*)(in + (size_t)(r0 + tr) * C + c0 + tc);
  t[tr][tc] = v.x; t[tr][tc + 1] = v.y; t[tr][tc + 2] = v.z; t[tr][tc + 3] = v.w;
  __syncthreads();
  const float s = (c0 + tr < scale_n) ? scale : 1.f;
  u32 p0 = (u32)f2bf(t[tc][tr] * s) | ((u32)f2bf(t[tc + 1][tr] * s) << 16);
  u32 p1 = (u32)f2bf(t[tc + 2][tr] * s) | ((u32)f2bf(t[tc + 3][tr] * s) << 16);
  u32* dst = (u32*)(out + (size_t)(c0 + tr) * R + r0 + tc);
  dst[0] = p0;
  dst[1] = p1;
}

// ---------------------------------------------------------------------------
// bf16 MFMA GEMM: C[M,N] = A[M,K] @ Bt[N,K]^T + bias (bias cols < bsn scaled
// by bsc).  128x128 tile, BK=32, 4 waves, global_load_lds, XOR-swizzled LDS.
// ---------------------------------------------------------------------------
template <int OUT_BF16>
__global__ __launch_bounds__(256) void gemm_mfma(
    const u16* __restrict__ A, const u16* __restrict__ Bt,
    const float* __restrict__ bias, void* __restrict__ Cv, int N, int K,
    int bsn, float bsc) {
  __shared__ u16 As[128 * 32];
  __shared__ u16 Bs[128 * 32];
  const int tid = threadIdx.x;
  const int l = tid & 63, g = l >> 4, lr = l & 15;
  const int w = tid >> 6;
  const int wm = (w >> 1) << 6, wn = (w & 1) << 6;
  const int bm = blockIdx.y << 7, bn = blockIdx.x << 7;

  f32x4 acc[4][4];
  const f32x4 zero = {0.f, 0.f, 0.f, 0.f};
#pragma unroll
  for (int i = 0; i < 4; ++i)
#pragma unroll
    for (int j = 0; j < 4; ++j) acc[i][j] = zero;

  const int bi0 = tid, bi1 = 256 + tid;
  const int r0 = bi0 >> 2, lb0 = (bi0 & 3) ^ ((r0 >> 1) & 3);
  const int r1 = bi1 >> 2, lb1 = (bi1 & 3) ^ ((r1 >> 1) & 3);
  const u16* a0 = A + (size_t)(bm + r0) * K + lb0 * 8;
  const u16* a1 = A + (size_t)(bm + r1) * K + lb1 * 8;
  const u16* b0 = Bt + (size_t)(bn + r0) * K + lb0 * 8;
  const u16* b1 = Bt + (size_t)(bn + r1) * K + lb1 * 8;

  const int swA = (lr >> 1) & 3;
  const int aoff = (wm + lr) * 64 + ((g ^ swA) << 4);
  const int boff = (wn + lr) * 64 + ((g ^ swA) << 4);

  for (int k0 = 0; k0 < K; k0 += 32) {
    __syncthreads();
    g2l16(a0 + k0, (char*)As + bi0 * 16);
    g2l16(a1 + k0, (char*)As + bi1 * 16);
    g2l16(b0 + k0, (char*)Bs + bi0 * 16);
    g2l16(b1 + k0, (char*)Bs + bi1 * 16);
    __syncthreads();
    bf16x8 af[4], bfv[4];
#pragma unroll
    for (int mi = 0; mi < 4; ++mi)
      af[mi] = *(const bf16x8*)((const char*)As + aoff + mi * 1024);
#pragma unroll
    for (int ni = 0; ni < 4; ++ni)
      bfv[ni] = *(const bf16x8*)((const char*)Bs + boff + ni * 1024);
#pragma unroll
    for (int mi = 0; mi < 4; ++mi)
#pragma unroll
      for (int ni = 0; ni < 4; ++ni)
        acc[mi][ni] = MFMA_16x16x32(af[mi], bfv[ni], acc[mi][ni]);
  }

  float bv[4];
#pragma unroll
  for (int ni = 0; ni < 4; ++ni) {
    const int col = bn + wn + ni * 16 + lr;
    bv[ni] = bias[col] * (col < bsn ? bsc : 1.f);
  }
  const int crow = bm + wm + (g << 2);
  const int ccol = bn + wn + lr;
  if (OUT_BF16) {
    u16* C = (u16*)Cv;
#pragma unroll
    for (int mi = 0; mi < 4; ++mi)
#pragma unroll
      for (int ni = 0; ni < 4; ++ni)
#pragma unroll
        for (int j = 0; j < 4; ++j)
          C[(size_t)(crow + mi * 16 + j) * N + ccol + ni * 16] =
              f2bf(acc[mi][ni][j] + bv[ni]);
  } else {
    float* C = (float*)Cv;
#pragma unroll
    for (int mi = 0; mi < 4; ++mi)
#pragma unroll
      for (int ni = 0; ni < 4; ++ni)
#pragma unroll
        for (int j = 0; j < 4; ++j)
          C[(size_t)(crow + mi * 16 + j) * N + ccol + ni * 16] =
              acc[mi][ni][j] + bv[ni];
  }
}

// ---------------------------------------------------------------------------
// V-transpose: qkv_b[.., 2048+h*64+d] -> vt[(b*16+h)*64+d][s]  (bf16)
// ---------------------------------------------------------------------------
__global__ __launch_bounds__(256) void vtrans(const u16* __restrict__ qkvb,
                                              u16* __restrict__ vt) {
  const int wid = (blockIdx.x << 2) + (threadIdx.x >> 6);
  const int l = threadIdx.x & 63;
  const int dc = wid & 7, st = (wid >> 3) & 31, h = (wid >> 8) & 15, b = wid >> 12;
  const int s = (st << 6) + l;
  const u16x8 v = *(const u16x8*)(qkvb + (size_t)(b * 2048 + s) * 3072 + 2048 + h * 64 + dc * 8);
  u16* dst = vt + ((size_t)(((b << 4) + h) << 6) + (dc << 3)) * 2048 + s;
#pragma unroll
  for (int j = 0; j < 8; ++j) dst[(size_t)j * 2048] = v[j];
}

// ---------------------------------------------------------------------------
// Flash attention, bf16 MFMA, swapped QK^T, scores pre-scaled to exp2 domain.
// Defer-max (THR=8 in log2 units): skip O-rescale when max doesn't grow.
// ---------------------------------------------------------------------------
__global__ __launch_bounds__(256) void attn_mfma(
    const u16* __restrict__ qkvb, const u16* __restrict__ vt,
    u16* __restrict__ attnb) {
  __shared__ u16 Qs[64 * 64];
  __shared__ u16 Ks[64 * 64];
  __shared__ u16 Vs[64 * 64];
  __shared__ u16 Ps[4][16 * 64];

  const int qt = blockIdx.x, h = blockIdx.y, b = blockIdx.z;
  const int tid = threadIdx.x, w = tid >> 6, l = tid & 63;
  const int g = l >> 4, lr = l & 15, sw = lr & 7;
  const size_t sb = (size_t)b * 2048;
  const f32x4 zero = {0.f, 0.f, 0.f, 0.f};

  const int bi0 = tid, bi1 = 256 + tid;
  const int sr0 = bi0 >> 3, slb0 = (bi0 & 7) ^ (sr0 & 7);
  const int sr1 = bi1 >> 3, slb1 = (bi1 & 7) ^ (sr1 & 7);

  {  // stage Q (rows = q, 64 cols hd); Q is pre-scaled by 0.125*log2e
    const u16* qb = qkvb + (sb + (size_t)qt * 64) * 3072 + h * 64;
    g2l16(qb + (size_t)sr0 * 3072 + slb0 * 8, (char*)Qs + bi0 * 16);
    g2l16(qb + (size_t)sr1 * 3072 + slb1 * 8, (char*)Qs + bi1 * 16);
  }
  __syncthreads();
  bf16x8 qf0, qf1;  // B-operand frags: lane q-col = lr
  {
    const int row = (w << 4) + lr;
    qf0 = *(const bf16x8*)((const char*)Qs + row * 128 + ((g ^ sw) << 4));
    qf1 = *(const bf16x8*)((const char*)Qs + row * 128 + (((4 + g) ^ sw) << 4));
  }

  float m_run = -1e30f, l_run = 0.f;
  f32x4 o[4];
#pragma unroll
  for (int i = 0; i < 4; ++i) o[i] = zero;

  const u16* kb = qkvb + sb * 3072 + 1024 + h * 64;
  const u16* vb = vt + ((size_t)((b << 4) + h) << 6) * 2048;
  u16* pw = &Ps[w][0];

  for (int kt = 0; kt < 32; ++kt) {
    __syncthreads();
    const size_t ko = (size_t)kt << 6;
    g2l16(kb + (ko + sr0) * 3072 + slb0 * 8, (char*)Ks + bi0 * 16);
    g2l16(kb + (ko + sr1) * 3072 + slb1 * 8, (char*)Ks + bi1 * 16);
    g2l16(vb + (size_t)sr0 * 2048 + ko + slb0 * 8, (char*)Vs + bi0 * 16);
    g2l16(vb + (size_t)sr1 * 2048 + ko + slb1 * 8, (char*)Vs + bi1 * 16);
    __syncthreads();

    // QK^T (swapped): St[f][j] = S^T[key = f*16 + g*4 + j][q = lr], exp2 domain
    f32x4 st[4];
#pragma unroll
    for (int f = 0; f < 4; ++f) {
      st[f] = zero;
      const char* krow = (const char*)Ks + (f * 16 + lr) * 128;
      const bf16x8 k0 = *(const bf16x8*)(krow + ((g ^ sw) << 4));
      const bf16x8 k1 = *(const bf16x8*)(krow + (((4 + g) ^ sw) << 4));
      st[f] = MFMA_16x16x32(k0, qf0, st[f]);
      st[f] = MFMA_16x16x32(k1, qf1, st[f]);
    }

    // online softmax for q = lr; defer-max: rescale only when max grows > 8
    float mx = -1e30f;
#pragma unroll
    for (int f = 0; f < 4; ++f)
#pragma unroll
      for (int j = 0; j < 4; ++j) mx = fmaxf(mx, st[f][j]);
    mx = fmaxf(mx, __shfl_xor(mx, 16));
    mx = fmaxf(mx, __shfl_xor(mx, 32));
    if (!__all(mx - m_run <= 8.f)) {
      const float m_new = fmaxf(m_run, mx);
      const float resc = exp2fast(m_run - m_new);
      float rs[4];
#pragma unroll
      for (int j = 0; j < 4; ++j) rs[j] = __shfl(resc, (g << 2) + j);
#pragma unroll
      for (int nf = 0; nf < 4; ++nf)
#pragma unroll
        for (int j = 0; j < 4; ++j) o[nf][j] *= rs[j];
      l_run *= resc;
      m_run = m_new;
    }
    float lsum = 0.f;
#pragma unroll
    for (int f = 0; f < 4; ++f)
#pragma unroll
      for (int j = 0; j < 4; ++j) {
        const float e = exp2fast(st[f][j] - m_run);
        st[f][j] = e;
        lsum += e;
      }
    lsum += __shfl_xor(lsum, 16);
    lsum += __shfl_xor(lsum, 32);
    l_run += lsum;

    // publish P[16q][64k] (bf16, block-swizzled by q&7), one b64 per frag
#pragma unroll
    for (int f = 0; f < 4; ++f) {
      u32x2 pv;
      pv[0] = (u32)f2bf(st[f][0]) | ((u32)f2bf(st[f][1]) << 16);
      pv[1] = (u32)f2bf(st[f][2]) | ((u32)f2bf(st[f][3]) << 16);
      const int pb = ((f << 1) + (g >> 1)) ^ sw;
      *(u32x2*)((char*)pw + lr * 128 + (pb << 4) + ((g & 1) << 3)) = pv;
    }
    asm volatile("" ::: "memory");  // order P write before P read

    // PV: O[16q][64d] += P[16q][64k] @ V[64k][64d]
    const bf16x8 pa0 = *(const bf16x8*)((const char*)pw + lr * 128 + ((g ^ sw) << 4));
    const bf16x8 pa1 = *(const bf16x8*)((const char*)pw + lr * 128 + (((4 + g) ^ sw) << 4));
#pragma unroll
    for (int nf = 0; nf < 4; ++nf) {
      const char* vrow = (const char*)Vs + (nf * 16 + lr) * 128;
      const bf16x8 v0 = *(const bf16x8*)(vrow + ((g ^ sw) << 4));
      const bf16x8 v1 = *(const bf16x8*)(vrow + (((4 + g) ^ sw) << 4));
      o[nf] = MFMA_16x16x32(pa0, v0, o[nf]);
      o[nf] = MFMA_16x16x32(pa1, v1, o[nf]);
    }
  }

  const float invl = 1.f / l_run;
  float iv[4];
#pragma unroll
  for (int j = 0; j < 4; ++j) iv[j] = __shfl(invl, (g << 2) + j);
  u16* obase = attnb + (sb + (size_t)qt * 64 + (w << 4)) * 1024 + h * 64;
#pragma unroll
  for (int nf = 0; nf < 4; ++nf)
#pragma unroll
    for (int j = 0; j < 4; ++j)
      obase[(size_t)((g << 2) + j) * 1024 + nf * 16 + lr] = f2bf(o[nf][j] * iv[j]);
}

// ---------------------------------------------------------------------------
extern "C" void kernel_launch(void* const* d_in, const int* in_sizes, int n_in,
                              void* d_out, int out_size, void* d_ws, size_t ws_size,
                              hipStream_t stream) {
  const float* x     = (const float*)d_in[0];  // [2,2048,1024]
  const float* w_qkv = (const float*)d_in[1];  // [1024,3072]
  const float* b_qkv = (const float*)d_in[2];  // [3072]
  const float* w_o   = (const float*)d_in[3];  // [1024,1024]
  const float* b_o   = (const float*)d_in[4];  // [1024]
  float* out = (float*)d_out;

  // workspace (bf16), 56 MB total
  u16* xb    = (u16*)d_ws;                       // 4096*1024
  u16* wqkvt = xb + (size_t)4096 * 1024;         // 3072*1024 (B^T)
  u16* wot   = wqkvt + (size_t)3072 * 1024;      // 1024*1024 (B^T)
  u16* qkvb  = wot + (size_t)1024 * 1024;        // 4096*3072
  u16* vtb   = qkvb + (size_t)4096 * 3072;       // 2*16*64*2048
  u16* attnb = vtb + (size_t)2 * 16 * 64 * 2048; // 4096*1024

  xcvt<<<dim3(2048), dim3(256), 0, stream>>>(x, xb, 4096 * 1024 / 8);
  // Q-columns (first 1024 of 3072) pre-scaled by 0.125*log2e -> exp2-domain scores
  wtrans<<<dim3(96, 32), dim3(256), 0, stream>>>(w_qkv, wqkvt, 1024, 3072, 1024, C_SCALE);
  wtrans<<<dim3(32, 32), dim3(256), 0, stream>>>(w_o, wot, 1024, 1024, 0, 1.f);

  gemm_mfma<1><<<dim3(24, 32), dim3(256), 0, stream>>>(xb, wqkvt, b_qkv, qkvb, 3072, 1024, 1024, C_SCALE);

  vtrans<<<dim3(2048), dim3(256), 0, stream>>>(qkvb, vtb);
  attn_mfma<<<dim3(32, 16, 2), dim3(256), 0, stream>>>(qkvb, vtb, attnb);

  gemm_mfma<0><<<dim3(8, 32), dim3(256), 0, stream>>>(attnb, wot, b_o, out, 1024, 1024, 0, 1.f);
}

// Round 5
// 142.526 us; speedup vs baseline: 12.3368x; 1.0962x over previous
//
#include <hip/hip_runtime.h>
#include <hip/hip_bf16.h>

typedef unsigned int u32;
typedef unsigned short u16;
typedef __attribute__((ext_vector_type(8))) short bf16x8;   // MFMA A/B frag (8 bf16)
typedef __attribute__((ext_vector_type(4))) float f32x4;
typedef __attribute__((ext_vector_type(16))) float f32x16;  // 32x32 MFMA C/D frag
typedef __attribute__((ext_vector_type(8))) u16 u16x8;
typedef __attribute__((ext_vector_type(2))) u32 u32x2;
typedef __attribute__((ext_vector_type(4))) u32 u32x4;

#define MFMA16(A, B, C) __builtin_amdgcn_mfma_f32_16x16x32_bf16(A, B, C, 0, 0, 0)
#define MFMA32(A, B, C) __builtin_amdgcn_mfma_f32_32x32x16_bf16(A, B, C, 0, 0, 0)

// 0.125 (1/sqrt(64)) * log2(e): folded into Q weights/bias -> scores in exp2 domain
#define C_SCALE 0.1803368801111244f

__device__ __forceinline__ u16 f2bf(float f) {   // RNE via native cast
  __hip_bfloat16 h = __float2bfloat16(f);
  u16 u;
  __builtin_memcpy(&u, &h, 2);
  return u;
}

__device__ __forceinline__ u32 pk2(float a, float b) {  // 2xbf16 pack (cvt_pk-able)
  return (u32)f2bf(a) | ((u32)f2bf(b) << 16);
}

__device__ __forceinline__ float exp2fast(float x) {
#if __has_builtin(__builtin_amdgcn_exp2f)
  return __builtin_amdgcn_exp2f(x);
#else
  return exp2f(x);
#endif
}

__device__ __forceinline__ u32x2 pl32swap(u32 a, u32 b) {
  return __builtin_amdgcn_permlane32_swap(a, b, false, false);
}

__device__ __forceinline__ void g2l16(const void* g, void* l) {
  __builtin_amdgcn_global_load_lds(
      (const __attribute__((address_space(1))) u32*)g,
      (__attribute__((address_space(3))) u32*)l, 16, 0, 0);
}

// ---------------------------------------------------------------------------
// x (fp32) -> bf16, 8 elems/thread
// ---------------------------------------------------------------------------
__global__ __launch_bounds__(256) void xcvt(const float* __restrict__ in,
                                            u16* __restrict__ out, int n8) {
  const int i = blockIdx.x * 256 + threadIdx.x;
  if (i >= n8) return;
  const float4* p = (const float4*)in + (size_t)i * 2;
  const float4 a = p[0], b = p[1];
  u16x8 o;
  o[0] = f2bf(a.x); o[1] = f2bf(a.y); o[2] = f2bf(a.z); o[3] = f2bf(a.w);
  o[4] = f2bf(b.x); o[5] = f2bf(b.y); o[6] = f2bf(b.z); o[7] = f2bf(b.w);
  *((u16x8*)out + i) = o;
}

// ---------------------------------------------------------------------------
// out[c][r] = bf16(in[r][c] * (c<scale_n ? scale : 1))  (weights -> B^T layout)
// ---------------------------------------------------------------------------
__global__ __launch_bounds__(256) void wtrans(const float* __restrict__ in,
                                              u16* __restrict__ out, int R, int C,
                                              int scale_n, float scale) {
  __shared__ float t[32][33];
  const int r0 = blockIdx.y << 5, c0 = blockIdx.x << 5;
  const int tr = threadIdx.x >> 3, tc = (threadIdx.x & 7) << 2;
  const float4 v = *(const float4*)(in + (size_t)(r0 + tr) * C + c0 + tc);
  t[tr][tc] = v.x; t[tr][tc + 1] = v.y; t[tr][tc + 2] = v.z; t[tr][tc + 3] = v.w;
  __syncthreads();
  const float s = (c0 + tr < scale_n) ? scale : 1.f;
  u32 p0 = pk2(t[tc][tr] * s, t[tc + 1][tr] * s);
  u32 p1 = pk2(t[tc + 2][tr] * s, t[tc + 3][tr] * s);
  u32* dst = (u32*)(out + (size_t)(c0 + tr) * R + r0 + tc);
  dst[0] = p0;
  dst[1] = p1;
}

// ---------------------------------------------------------------------------
// bf16 MFMA GEMM: C[M,N] = A[M,K] @ Bt[N,K]^T + bias.  128x128 tile, BK=32,
// 4 waves, global_load_lds, XOR-swizzled LDS.  (unchanged from round 4)
// ---------------------------------------------------------------------------
template <int OUT_BF16>
__global__ __launch_bounds__(256) void gemm_mfma(
    const u16* __restrict__ A, const u16* __restrict__ Bt,
    const float* __restrict__ bias, void* __restrict__ Cv, int N, int K,
    int bsn, float bsc) {
  __shared__ u16 As[128 * 32];
  __shared__ u16 Bs[128 * 32];
  const int tid = threadIdx.x;
  const int l = tid & 63, g = l >> 4, lr = l & 15;
  const int w = tid >> 6;
  const int wm = (w >> 1) << 6, wn = (w & 1) << 6;
  const int bm = blockIdx.y << 7, bn = blockIdx.x << 7;

  f32x4 acc[4][4];
  const f32x4 zero = {0.f, 0.f, 0.f, 0.f};
#pragma unroll
  for (int i = 0; i < 4; ++i)
#pragma unroll
    for (int j = 0; j < 4; ++j) acc[i][j] = zero;

  const int bi0 = tid, bi1 = 256 + tid;
  const int r0 = bi0 >> 2, lb0 = (bi0 & 3) ^ ((r0 >> 1) & 3);
  const int r1 = bi1 >> 2, lb1 = (bi1 & 3) ^ ((r1 >> 1) & 3);
  const u16* a0 = A + (size_t)(bm + r0) * K + lb0 * 8;
  const u16* a1 = A + (size_t)(bm + r1) * K + lb1 * 8;
  const u16* b0 = Bt + (size_t)(bn + r0) * K + lb0 * 8;
  const u16* b1 = Bt + (size_t)(bn + r1) * K + lb1 * 8;

  const int swA = (lr >> 1) & 3;
  const int aoff = (wm + lr) * 64 + ((g ^ swA) << 4);
  const int boff = (wn + lr) * 64 + ((g ^ swA) << 4);

  for (int k0 = 0; k0 < K; k0 += 32) {
    __syncthreads();
    g2l16(a0 + k0, (char*)As + bi0 * 16);
    g2l16(a1 + k0, (char*)As + bi1 * 16);
    g2l16(b0 + k0, (char*)Bs + bi0 * 16);
    g2l16(b1 + k0, (char*)Bs + bi1 * 16);
    __syncthreads();
    bf16x8 af[4], bfv[4];
#pragma unroll
    for (int mi = 0; mi < 4; ++mi)
      af[mi] = *(const bf16x8*)((const char*)As + aoff + mi * 1024);
#pragma unroll
    for (int ni = 0; ni < 4; ++ni)
      bfv[ni] = *(const bf16x8*)((const char*)Bs + boff + ni * 1024);
#pragma unroll
    for (int mi = 0; mi < 4; ++mi)
#pragma unroll
      for (int ni = 0; ni < 4; ++ni)
        acc[mi][ni] = MFMA16(af[mi], bfv[ni], acc[mi][ni]);
  }

  float bv[4];
#pragma unroll
  for (int ni = 0; ni < 4; ++ni) {
    const int col = bn + wn + ni * 16 + lr;
    bv[ni] = bias[col] * (col < bsn ? bsc : 1.f);
  }
  const int crow = bm + wm + (g << 2);
  const int ccol = bn + wn + lr;
  if (OUT_BF16) {
    u16* C = (u16*)Cv;
#pragma unroll
    for (int mi = 0; mi < 4; ++mi)
#pragma unroll
      for (int ni = 0; ni < 4; ++ni)
#pragma unroll
        for (int j = 0; j < 4; ++j)
          C[(size_t)(crow + mi * 16 + j) * N + ccol + ni * 16] =
              f2bf(acc[mi][ni][j] + bv[ni]);
  } else {
    float* C = (float*)Cv;
#pragma unroll
    for (int mi = 0; mi < 4; ++mi)
#pragma unroll
      for (int ni = 0; ni < 4; ++ni)
#pragma unroll
        for (int j = 0; j < 4; ++j)
          C[(size_t)(crow + mi * 16 + j) * N + ccol + ni * 16] =
              acc[mi][ni][j] + bv[ni];
  }
}

// ---------------------------------------------------------------------------
// V-transpose: qkv_b[.., 2048+h*64+d] -> vt[(b*16+h)*64+d][s]  (bf16)
// ---------------------------------------------------------------------------
__global__ __launch_bounds__(256) void vtrans(const u16* __restrict__ qkvb,
                                              u16* __restrict__ vt) {
  const int wid = (blockIdx.x << 2) + (threadIdx.x >> 6);
  const int l = threadIdx.x & 63;
  const int dc = wid & 7, st = (wid >> 3) & 31, h = (wid >> 8) & 15, b = wid >> 12;
  const int s = (st << 6) + l;
  const u16x8 v = *(const u16x8*)(qkvb + (size_t)(b * 2048 + s) * 3072 + 2048 + h * 64 + dc * 8);
  u16* dst = vt + ((size_t)(((b << 4) + h) << 6) + (dc << 3)) * 2048 + s;
#pragma unroll
  for (int j = 0; j < 8; ++j) dst[(size_t)j * 2048] = v[j];
}

// ---------------------------------------------------------------------------
// Flash attention, 32x32x16 MFMA, swapped QK^T, in-register softmax + P
// (permlane32_swap redistribution; P never touches LDS).
// Block = (q-tile 128, head, batch); 4 waves x 32 q-rows.
// Lane l: q = l&31, hw = l>>5.  St[kb] C-frag: col=q, key=32kb+(r&3)+8(r>>2)+4hw.
// PV A-frag pa[kc] elem e: key = 16kc+8hw+e  (built from st via 2 swaps/chunk).
// ---------------------------------------------------------------------------
__global__ __launch_bounds__(256, 2) void attn_mfma(
    const u16* __restrict__ qkvb, const u16* __restrict__ vt,
    u16* __restrict__ attnb) {
  __shared__ u16 Qs[128 * 64];
  __shared__ u16 Ks[64 * 64];
  __shared__ u16 Vs[64 * 64];

  const int qt = blockIdx.x, head = blockIdx.y, b = blockIdx.z;
  const int tid = threadIdx.x, w = tid >> 6, l = tid & 63;
  const int lq = l & 31, hw = l >> 5;
  const size_t sb = (size_t)b * 2048;
  const f32x16 z16 = {};

  // stage Q[128 q][64 d], block-swizzle ^ (row&7)
  {
    const u16* qb = qkvb + (sb + (size_t)qt * 128) * 3072 + head * 64;
#pragma unroll
    for (int j = 0; j < 4; ++j) {
      const int qi = tid + 256 * j;
      const int r = qi >> 3, blk = (qi & 7) ^ (r & 7);
      g2l16(qb + (size_t)r * 3072 + blk * 8, (char*)Qs + qi * 16);
    }
  }
  const int bi0 = tid, bi1 = 256 + tid;
  const int sr0 = bi0 >> 3, slb0 = (bi0 & 7) ^ (sr0 & 7);
  const int sr1 = bi1 >> 3, slb1 = (bi1 & 7) ^ (sr1 & 7);

  __syncthreads();
  // Q frags (B-operand): col q = lq (abs row 32w+lq), k = d = 16dc+8hw+e
  bf16x8 qf[4];
  {
    const int row = (w << 5) + lq;
#pragma unroll
    for (int dc = 0; dc < 4; ++dc)
      qf[dc] = *(const bf16x8*)((const char*)Qs + row * 128 +
                                (((2 * dc + hw) ^ (row & 7)) << 4));
  }

  float m_run = -1e30f, l_run = 0.f;
  f32x16 o0 = z16, o1 = z16;

  const u16* kbase = qkvb + sb * 3072 + 1024 + head * 64;
  const u16* vbase = vt + ((size_t)((b << 4) + head) << 6) * 2048;

  for (int kt = 0; kt < 32; ++kt) {
    __syncthreads();
    const size_t ko = (size_t)kt << 6;
    g2l16(kbase + (ko + sr0) * 3072 + slb0 * 8, (char*)Ks + bi0 * 16);
    g2l16(kbase + (ko + sr1) * 3072 + slb1 * 8, (char*)Ks + bi1 * 16);
    g2l16(vbase + (size_t)sr0 * 2048 + ko + slb0 * 8, (char*)Vs + bi0 * 16);
    g2l16(vbase + (size_t)sr1 * 2048 + ko + slb1 * 8, (char*)Vs + bi1 * 16);
    __syncthreads();

    // QK^T (swapped): st[kb] = S^T[keys 32kb..+31][q 32 cols], exp2 domain
    f32x16 st0 = z16, st1 = z16;
#pragma unroll
    for (int dc = 0; dc < 4; ++dc) {
      const int blk = 2 * dc + hw;
      const bf16x8 k0 = *(const bf16x8*)((const char*)Ks + lq * 128 +
                                         ((blk ^ (lq & 7)) << 4));
      st0 = MFMA32(k0, qf[dc], st0);
      const bf16x8 k1 = *(const bf16x8*)((const char*)Ks + (32 + lq) * 128 +
                                         ((blk ^ (lq & 7)) << 4));
      st1 = MFMA32(k1, qf[dc], st1);
    }

    // in-register online softmax for q = lq (cross-half via permlane32_swap)
    float mx = st0[0];
#pragma unroll
    for (int i = 1; i < 16; ++i) mx = fmaxf(mx, st0[i]);
#pragma unroll
    for (int i = 0; i < 16; ++i) mx = fmaxf(mx, st1[i]);
    {
      const u32x2 r = pl32swap(__float_as_uint(mx), __float_as_uint(mx));
      mx = fmaxf(__uint_as_float(r.x), __uint_as_float(r.y));
    }
    if (!__all(mx - m_run <= 8.f)) {   // defer-max: rescale only when max grows
      const float m_new = fmaxf(m_run, mx);
      const float resc = exp2fast(m_run - m_new);
      float rs[16];
#pragma unroll
      for (int r = 0; r < 16; ++r)
        rs[r] = __shfl(resc, (r & 3) + 8 * (r >> 2) + 4 * hw);
#pragma unroll
      for (int r = 0; r < 16; ++r) { o0[r] *= rs[r]; o1[r] *= rs[r]; }
      l_run *= resc;
      m_run = m_new;
    }
    float lsum = 0.f;
#pragma unroll
    for (int i = 0; i < 16; ++i) { st0[i] = exp2fast(st0[i] - m_run); lsum += st0[i]; }
#pragma unroll
    for (int i = 0; i < 16; ++i) { st1[i] = exp2fast(st1[i] - m_run); lsum += st1[i]; }
    {
      const u32x2 r = pl32swap(__float_as_uint(lsum), __float_as_uint(lsum));
      lsum = __uint_as_float(r.x) + __uint_as_float(r.y);
    }
    l_run += lsum;

    // pack P -> PV A-frags: pa[kc] elem e holds key 16kc+8hw+e for q=lq.
    // swap(pk(r0,r1), pk(r4,r5)) -> (.x = word0, .y = word2) for BOTH halves.
    bf16x8 pa[4];
#pragma unroll
    for (int kc = 0; kc < 4; ++kc) {
      const f32x16 s = (kc < 2) ? st0 : st1;
      const int q0 = (kc & 1) * 8;
      const u32 W01 = pk2(s[q0 + 0], s[q0 + 1]);
      const u32 W23 = pk2(s[q0 + 2], s[q0 + 3]);
      const u32 W45 = pk2(s[q0 + 4], s[q0 + 5]);
      const u32 W67 = pk2(s[q0 + 6], s[q0 + 7]);
      const u32x2 rA = pl32swap(W01, W45);
      const u32x2 rB = pl32swap(W23, W67);
      const u32x4 wds = {rA.x, rB.x, rA.y, rB.y};
      pa[kc] = __builtin_bit_cast(bf16x8, wds);
    }

    // PV: O[32q][64d] += P @ V.  B-frag: col d = 32nb+lq, k = key 16kc+8hw+e
#pragma unroll
    for (int kc = 0; kc < 4; ++kc) {
      const int blk = 2 * kc + hw;
      const bf16x8 v0 = *(const bf16x8*)((const char*)Vs + lq * 128 +
                                         ((blk ^ (lq & 7)) << 4));
      o0 = MFMA32(pa[kc], v0, o0);
      const bf16x8 v1 = *(const bf16x8*)((const char*)Vs + (32 + lq) * 128 +
                                         ((blk ^ (lq & 7)) << 4));
      o1 = MFMA32(pa[kc], v1, o1);
    }
  }

  // epilogue: O rows q = (r&3)+8(r>>2)+4hw, cols d = 32nb+lq
  const float invl = 1.f / l_run;
  u16* ob = attnb + (sb + (size_t)qt * 128 + (w << 5)) * 1024 + head * 64;
#pragma unroll
  for (int r = 0; r < 16; ++r) {
    const int qo = (r & 3) + 8 * (r >> 2) + 4 * hw;
    const float iv = __shfl(invl, qo);
    ob[(size_t)qo * 1024 + lq] = f2bf(o0[r] * iv);
    ob[(size_t)qo * 1024 + 32 + lq] = f2bf(o1[r] * iv);
  }
}

// ---------------------------------------------------------------------------
extern "C" void kernel_launch(void* const* d_in, const int* in_sizes, int n_in,
                              void* d_out, int out_size, void* d_ws, size_t ws_size,
                              hipStream_t stream) {
  const float* x     = (const float*)d_in[0];  // [2,2048,1024]
  const float* w_qkv = (const float*)d_in[1];  // [1024,3072]
  const float* b_qkv = (const float*)d_in[2];  // [3072]
  const float* w_o   = (const float*)d_in[3];  // [1024,1024]
  const float* b_o   = (const float*)d_in[4];  // [1024]
  float* out = (float*)d_out;

  // workspace (bf16), 56 MB total
  u16* xb    = (u16*)d_ws;                       // 4096*1024
  u16* wqkvt = xb + (size_t)4096 * 1024;         // 3072*1024 (B^T)
  u16* wot   = wqkvt + (size_t)3072 * 1024;      // 1024*1024 (B^T)
  u16* qkvb  = wot + (size_t)1024 * 1024;        // 4096*3072
  u16* vtb   = qkvb + (size_t)4096 * 3072;       // 2*16*64*2048
  u16* attnb = vtb + (size_t)2 * 16 * 64 * 2048; // 4096*1024

  xcvt<<<dim3(2048), dim3(256), 0, stream>>>(x, xb, 4096 * 1024 / 8);
  // Q-columns (first 1024 of 3072) pre-scaled by 0.125*log2e -> exp2-domain scores
  wtrans<<<dim3(96, 32), dim3(256), 0, stream>>>(w_qkv, wqkvt, 1024, 3072, 1024, C_SCALE);
  wtrans<<<dim3(32, 32), dim3(256), 0, stream>>>(w_o, wot, 1024, 1024, 0, 1.f);

  gemm_mfma<1><<<dim3(24, 32), dim3(256), 0, stream>>>(xb, wqkvt, b_qkv, qkvb, 3072, 1024, 1024, C_SCALE);

  vtrans<<<dim3(2048), dim3(256), 0, stream>>>(qkvb, vtb);
  attn_mfma<<<dim3(16, 16, 2), dim3(256), 0, stream>>>(qkvb, vtb, attnb);

  gemm_mfma<0><<<dim3(8, 32), dim3(256), 0, stream>>>(attnb, wot, b_o, out, 1024, 1024, 0, 1.f);
}